// Round 1
// baseline (345.715 us; speedup 1.0000x reference)
//
#include <hip/hip_runtime.h>
#include <hip/hip_cooperative_groups.h>
#include <cstddef>

namespace cg = cooperative_groups;

#define TB    512
#define NSTEP 10
// Problem constants: N=4096, E=65536 (=N*16, uniform degree 16, row-major
// sorted so out-edges of node i are slots [16i,16i+16)), Eu=32768.
// Slot scheme: em buffer slot g (g=16i+t) holds the message on edge
// rev[g]=(j->i), so node i's incoming messages are slots [16i,16i+16).
// We propagate u = hidden + lnZ; hidden recovered as u - lse(u) at readout.
// R7: single cooperative kernel. All 12 former dispatches fused; per-edge
// (j,rev,js,C) and per-node (1/dom, bias_scale, ci) stay in registers for
// all 10 BP steps; grid.sync() between phases. rsj via fA[j] (one 8B load)
// instead of 16 scattered J gathers. Epilogue operands prefetched pre-loop.

__device__ __forceinline__ float lse2(float a, float b) {
    return fmaxf(a, b) + __logf(1.0f + __expf(-fabsf(a - b)));
}

struct KParams {
    const float *J, *bias, *gat_W, *gat_a, *W1, *b1, *W2, *b2, *W3, *b3;
    const int *col, *rev, *ru, *cu, *u2e;
    int N, Eu;
    int4*   edgeP;
    float2 *fA, *uA, *uB, *emA, *emB;
    float  *ci_out, *dom_out, *ent;
    float2* ro_out;
    float4* rp_out;
    float*  cij_out;
};

__global__ __launch_bounds__(TB) void k_fused(KParams p) {
    __shared__ float sW2[64 * 64];
    __shared__ float sh1[TB / 16][65];
    __shared__ float red[TB / 64];
    cg::grid_group grid = cg::this_grid();

    const int tidb = threadIdx.x;
    const int g = blockIdx.x * TB + tidb;
    const int i = g >> 4, t = g & 15;
    const int lane = tidb & 63;

    // ---------------- phase A: per-node quantities --------------------------
    for (int k = tidb; k < 64 * 64; k += TB) sW2[k] = p.W2[k];
    if (g < 3) p.ent[g] = 0.0f;
    p.emA[g] = make_float2(0.0f, 0.0f);      // em0 = log(1) = 0

    const int j  = p.col[g];
    const int rg = p.rev[g];
    const float Jv = p.J[(size_t)i * (size_t)p.N + (size_t)j];

    float rs = Jv;                            // row-sum of node i (16 nnz)
    rs += __shfl_xor(rs, 1); rs += __shfl_xor(rs, 2);
    rs += __shfl_xor(rs, 4); rs += __shfl_xor(rs, 8);

    const float bi = p.bias[i];

    float s8 = 0.0f;                          // gat_W^T @ gat_a halves
    if (lane < 8) {
        int k = lane & 3;
        const float* a = p.gat_a + ((lane < 4) ? 0 : 64);
        for (int h = 0; h < 64; ++h) s8 += p.gat_W[k * 64 + h] * a[h];
    }
    const float w10 = __shfl(s8, 0), w11 = __shfl(s8, 1), w12 = __shfl(s8, 2), w13 = __shfl(s8, 3);
    const float w20 = __shfl(s8, 4), w21 = __shfl(s8, 5), w22 = __shfl(s8, 6), w23 = __shfl(s8, 7);
    const float fd = 16.0f;
    const float f1i = -bi * w10 + bi * w11 + fd * w12 + rs * w13;
    const float f2i = -bi * w20 + bi * w21 + fd * w22 + rs * w23;

    // Ci readout MLP (per node, 16 threads per node)
    const int nib = tidb >> 4;
    __syncthreads();                          // sW2 staged
    #pragma unroll
    for (int m = 0; m < 4; ++m) {
        int h = t + 16 * m;
        float a = -bi * p.W1[h] + bi * p.W1[64 + h] + fd * p.W1[128 + h]
                + rs * p.W1[192 + h] + p.b1[h];
        sh1[nib][h] = fmaxf(a, 0.0f);
    }
    __syncthreads();
    float civ = 0.0f;
    #pragma unroll
    for (int m = 0; m < 4; ++m) {
        int o = t + 16 * m;
        float acc = p.b2[o];
        for (int h = 0; h < 64; ++h) acc += sh1[nib][h] * sW2[h * 64 + o];
        civ += fmaxf(acc, 0.0f) * p.W3[o];
    }
    civ += __shfl_xor(civ, 1); civ += __shfl_xor(civ, 2);
    civ += __shfl_xor(civ, 4); civ += __shfl_xor(civ, 8);
    const float ci = civ + p.b3[0];

    if (t == 0) {
        p.fA[i] = make_float2(f1i, f2i);
        p.ci_out[i] = ci;
    }
    grid.sync();                              // (1) fA, em0 visible

    // ---------------- phase B: per-edge params + dom ------------------------
    const float2 fj = p.fA[j];                // f1/f2 of neighbor (1 load)
    float x1 = f1i + fj.y; x1 = (x1 > 0.0f) ? x1 : 0.2f * x1;
    float x2 = fj.x + f2i; x2 = (x2 > 0.0f) ? x2 : 0.2f * x2;
    const float C  = 0.5f * (__expf(x1) + __expf(x2));   // symmetric g <-> rev[g]
    const float js = Jv / C;
    p.edgeP[g] = make_int4(j, rg, __float_as_int(js), __float_as_int(C));

    float sc = C;
    sc += __shfl_xor(sc, 1); sc += __shfl_xor(sc, 2);
    sc += __shfl_xor(sc, 4); sc += __shfl_xor(sc, 8);
    const float s  = ci + sc;
    const float cl = fmaxf(fabsf(s), 0.1f);
    const float d  = (s > 0.0f) ? cl : ((s < 0.0f) ? -cl : 0.0f);
    const float rd = 1.0f / d;
    const float bs = bi * rd;
    if (t == 0) {
        p.dom_out[i] = d;
        p.uA[i] = make_float2(-bs, bs);       // u0 = bx_scale (em0 = 0)
    }
    grid.sync();                              // (2) uA, edgeP visible

    // prefetch epilogue operands (independent of BP steps)
    int eE = 0, eR = 0, eC = 0, eEr = 0;
    float jse = 0.0f, Ce = 0.0f;
    if (g < p.Eu) {
        eE = p.u2e[g]; eR = p.ru[g]; eC = p.cu[g];
        const int4 ep = p.edgeP[eE];
        eEr = ep.y; jse = __int_as_float(ep.z); Ce = __int_as_float(ep.w);
    }

    // ---------------- BP steps (all state in registers) ---------------------
    float2 *uP = p.uA, *uQ = p.uB, *emP = p.emA, *emQ = p.emB;
    for (int st = 0; st < NSTEP; ++st) {
        const float2 uj = uP[j];              // two independent 8B gathers
        const float2 mu = emP[rg];
        const float a0 = uj.x - mu.x, a1 = uj.y - mu.y;
        const float t0 = fmaxf( js + a0, -js + a1);
        const float t1 = fmaxf(-js + a0,  js + a1);
        const float ls = lse2(t0, t1);
        const float e0 = C * (t0 - ls), e1 = C * (t1 - ls);
        emQ[g] = make_float2(e0, e1);

        float nm0 = e0, nm1 = e1;             // node's 16 incoming messages
        nm0 += __shfl_xor(nm0, 1); nm1 += __shfl_xor(nm1, 1);
        nm0 += __shfl_xor(nm0, 2); nm1 += __shfl_xor(nm1, 2);
        nm0 += __shfl_xor(nm0, 4); nm1 += __shfl_xor(nm1, 4);
        nm0 += __shfl_xor(nm0, 8); nm1 += __shfl_xor(nm1, 8);
        const float v0 = -bs + nm0 * rd, v1 = bs + nm1 * rd;
        if (t == 0) uQ[i] = make_float2(v0, v1);

        if (st == NSTEP - 1) {                // node readout + node entropy
            float nodeC = 0.0f;
            if (t == 0) {
                const float lz = lse2(v0, v1);
                const float r0 = __expf(v0 - lz), r1 = __expf(v1 - lz);
                p.ro_out[i] = make_float2(r0, r1);
                const float H = -(r0 * __logf(r0 + 1e-16f) + r1 * __logf(r1 + 1e-16f));
                nodeC = ci * H;
            }
            for (int off = 32; off > 0; off >>= 1) nodeC += __shfl_down(nodeC, off);
            const int wv = tidb >> 6;
            if (lane == 0) red[wv] = nodeC;
            __syncthreads();
            if (tidb == 0) {
                float sn = 0.0f;
                #pragma unroll
                for (int w = 0; w < TB / 64; ++w) sn += red[w];
                atomicAdd(&p.ent[0], sn);
                atomicAdd(&p.ent[1], sn);
            }
        }
        grid.sync();                          // step s results visible
        float2* tp;
        tp = uP;  uP  = uQ;  uQ  = tp;
        tp = emP; emP = emQ; emQ = tp;
    }
    // uP/emP now hold final values

    // ---------------- epilogue: pairwise readout + edge entropy -------------
    float edgeC = 0.0f;
    if (g < p.Eu) {
        const float2 uc = uP[eC], ur = uP[eR];
        const float lc = lse2(uc.x, uc.y);
        const float lr = lse2(ur.x, ur.y);
        const float2 eme = emP[eEr];          // message on edge e at slot rev[e]
        const float2 emr = emP[eE];           // message on rev[e] at slot e
        const float ti0 = (uc.x - lc) - eme.x, ti1 = (uc.y - lc) - eme.y;
        const float tj0 = (ur.x - lr) - emr.x, tj1 = (ur.y - lr) - emr.y;
        const float L00 =  jse + ti0 + tj0;
        const float L01 = -jse + ti1 + tj0;
        const float L10 = -jse + ti0 + tj1;
        const float L11 =  jse + ti1 + tj1;
        const float mL = fmaxf(fmaxf(L00, L01), fmaxf(L10, L11));
        float p00 = __expf(L00 - mL), p01 = __expf(L01 - mL);
        float p10 = __expf(L10 - mL), p11 = __expf(L11 - mL);
        const float inv = 1.0f / (p00 + p01 + p10 + p11);
        p00 *= inv; p01 *= inv; p10 *= inv; p11 *= inv;
        p.rp_out[g] = make_float4(p00, p01, p10, p11);
        p.cij_out[g] = Ce;
        const float H = -(p00 * __logf(p00 + 1e-16f) + p01 * __logf(p01 + 1e-16f)
                        + p10 * __logf(p10 + 1e-16f) + p11 * __logf(p11 + 1e-16f));
        edgeC = Ce * H;
    }
    for (int off = 32; off > 0; off >>= 1) edgeC += __shfl_down(edgeC, off);
    const int wv = tidb >> 6;
    if (lane == 0) red[wv] = edgeC;
    __syncthreads();
    if (tidb == 0) {
        float se = 0.0f;
        #pragma unroll
        for (int w = 0; w < TB / 64; ++w) se += red[w];
        atomicAdd(&p.ent[0], se);
        atomicAdd(&p.ent[2], se);
    }
}

extern "C" void kernel_launch(void* const* d_in, const int* in_sizes, int n_in,
                              void* d_out, int out_size, void* d_ws, size_t ws_size,
                              hipStream_t stream) {
    const int N  = in_sizes[1];
    const int E  = in_sizes[10];
    const int Eu = in_sizes[13];

    float* out = (float*)d_out;
    size_t OFF_RP  = 2 * (size_t)N;
    size_t OFF_ENT = OFF_RP + 4 * (size_t)Eu;

    char* w = (char*)d_ws;
    auto carve = [&](size_t bytes) {
        void* q = (void*)w;
        w += (bytes + 255) & ~(size_t)255;
        return q;
    };

    KParams p;
    p.J     = (const float*)d_in[0];
    p.bias  = (const float*)d_in[1];
    p.gat_W = (const float*)d_in[2];
    p.gat_a = (const float*)d_in[3];
    p.W1    = (const float*)d_in[4];
    p.b1    = (const float*)d_in[5];
    p.W2    = (const float*)d_in[6];
    p.b2    = (const float*)d_in[7];
    p.W3    = (const float*)d_in[8];
    p.b3    = (const float*)d_in[9];
    p.col   = (const int*)d_in[11];
    p.rev   = (const int*)d_in[12];
    p.ru    = (const int*)d_in[13];
    p.cu    = (const int*)d_in[14];
    p.u2e   = (const int*)d_in[15];
    p.N = N; p.Eu = Eu;

    p.edgeP = (int4*)carve((size_t)E * 16);
    p.fA    = (float2*)carve((size_t)N * 8);
    p.uA    = (float2*)carve((size_t)N * 8);
    p.uB    = (float2*)carve((size_t)N * 8);
    p.emA   = (float2*)carve((size_t)E * 8);
    p.emB   = (float2*)carve((size_t)E * 8);

    p.ro_out  = (float2*)out;
    p.rp_out  = (float4*)(out + OFF_RP);
    p.ent     = out + OFF_ENT;
    p.ci_out  = p.ent + 3;
    p.cij_out = p.ci_out + N;
    p.dom_out = p.cij_out + Eu;

    const int nb = E / TB;   // 128 blocks x 512 threads, co-resident
    void* args[] = { (void*)&p };
    hipLaunchCooperativeKernel((const void*)k_fused, dim3(nb), dim3(TB),
                               args, 0, stream);
}

// Round 2
// 212.425 us; speedup vs baseline: 1.6275x; 1.6275x over previous
//
#include <hip/hip_runtime.h>
#include <cstddef>

#define TB    1024
#define NB    64
#define NSTEP 10
// Problem constants: N=4096, E=65536 (=N*16, uniform degree 16, row-major
// sorted so out-edges of node i are slots [16i,16i+16)), Eu=32768.
// Slot scheme: em buffer slot g (g=16i+t) holds the message on edge
// rev[g]=(j->i), so node i's incoming messages are slots [16i,16i+16).
// We propagate u = hidden + lnZ; hidden recovered as u - lse(u) at readout.
// R8: single fused kernel with HAND-ROLLED grid barrier (cg::grid.sync was
// ~14us/sync -> kernel 203us). Regular launch (64 blocks x 1024 thr, >=1
// block/CU by capacity => co-resident). Per-barrier counter, agent-scope
// release/acquire via __threadfence, relaxed polls + s_sleep backoff.

__device__ __forceinline__ float lse2(float a, float b) {
    return fmaxf(a, b) + __logf(1.0f + __expf(-fabsf(a - b)));
}

struct KParams {
    const float *J, *bias, *gat_W, *gat_a, *W1, *b1, *W2, *b2, *W3, *b3;
    const int *col, *rev, *ru, *cu, *u2e;
    int N, Eu;
    int4*   edgeP;
    float2 *fA, *uA, *uB, *emA, *emB;
    int*    bar;                 // 16 counters, 128B apart, pre-zeroed
    float  *ci_out, *dom_out, *ent;
    float2* ro_out;
    float4* rp_out;
    float*  cij_out;
};

// Centralized grid barrier. __syncthreads() drains each wave's vmem stores
// (HIP emits s_waitcnt vmcnt(0) before s_barrier); thread 0 then does the
// agent-scope release (L2 writeback), arrives, polls relaxed, acquires.
__device__ __forceinline__ void grid_bar(int* bar, int idx) {
    __syncthreads();
    if (threadIdx.x == 0) {
        __threadfence();                       // release: wb L2 (agent scope)
        __hip_atomic_fetch_add(&bar[idx * 32], 1, __ATOMIC_RELAXED,
                               __HIP_MEMORY_SCOPE_AGENT);
        while (__hip_atomic_load(&bar[idx * 32], __ATOMIC_RELAXED,
                                 __HIP_MEMORY_SCOPE_AGENT) < NB)
            __builtin_amdgcn_s_sleep(1);
        __threadfence();                       // acquire: inv stale L1/L2
    }
    __syncthreads();
}

__global__ __launch_bounds__(TB) void k_fused(KParams p) {
    __shared__ float sW2[64 * 64];
    __shared__ float sh1[TB / 16][65];
    __shared__ float red[TB / 64];

    const int tidb = threadIdx.x;
    const int g = blockIdx.x * TB + tidb;
    const int i = g >> 4, t = g & 15;
    const int lane = tidb & 63;

    // ---------------- phase A: per-node quantities --------------------------
    for (int k = tidb; k < 64 * 64; k += TB) sW2[k] = p.W2[k];
    if (g < 3) p.ent[g] = 0.0f;
    p.emA[g] = make_float2(0.0f, 0.0f);      // em0 = log(1) = 0

    const int j  = p.col[g];
    const int rg = p.rev[g];
    const float Jv = p.J[(size_t)i * (size_t)p.N + (size_t)j];

    float rs = Jv;                            // row-sum of node i (16 nnz)
    rs += __shfl_xor(rs, 1); rs += __shfl_xor(rs, 2);
    rs += __shfl_xor(rs, 4); rs += __shfl_xor(rs, 8);

    const float bi = p.bias[i];

    float s8 = 0.0f;                          // gat_W^T @ gat_a halves
    if (lane < 8) {
        int k = lane & 3;
        const float* a = p.gat_a + ((lane < 4) ? 0 : 64);
        for (int h = 0; h < 64; ++h) s8 += p.gat_W[k * 64 + h] * a[h];
    }
    const float w10 = __shfl(s8, 0), w11 = __shfl(s8, 1), w12 = __shfl(s8, 2), w13 = __shfl(s8, 3);
    const float w20 = __shfl(s8, 4), w21 = __shfl(s8, 5), w22 = __shfl(s8, 6), w23 = __shfl(s8, 7);
    const float fd = 16.0f;
    const float f1i = -bi * w10 + bi * w11 + fd * w12 + rs * w13;
    const float f2i = -bi * w20 + bi * w21 + fd * w22 + rs * w23;

    // Ci readout MLP (per node, 16 threads per node)
    const int nib = tidb >> 4;
    __syncthreads();                          // sW2 staged
    #pragma unroll
    for (int m = 0; m < 4; ++m) {
        int h = t + 16 * m;
        float a = -bi * p.W1[h] + bi * p.W1[64 + h] + fd * p.W1[128 + h]
                + rs * p.W1[192 + h] + p.b1[h];
        sh1[nib][h] = fmaxf(a, 0.0f);
    }
    __syncthreads();
    float civ = 0.0f;
    #pragma unroll
    for (int m = 0; m < 4; ++m) {
        int o = t + 16 * m;
        float acc = p.b2[o];
        for (int h = 0; h < 64; ++h) acc += sh1[nib][h] * sW2[h * 64 + o];
        civ += fmaxf(acc, 0.0f) * p.W3[o];
    }
    civ += __shfl_xor(civ, 1); civ += __shfl_xor(civ, 2);
    civ += __shfl_xor(civ, 4); civ += __shfl_xor(civ, 8);
    const float ci = civ + p.b3[0];

    if (t == 0) {
        p.fA[i] = make_float2(f1i, f2i);
        p.ci_out[i] = ci;
    }
    grid_bar(p.bar, 0);                       // (1) fA, em0 visible

    // ---------------- phase B: per-edge params + dom ------------------------
    const float2 fj = p.fA[j];                // f1/f2 of neighbor (1 load)
    float x1 = f1i + fj.y; x1 = (x1 > 0.0f) ? x1 : 0.2f * x1;
    float x2 = fj.x + f2i; x2 = (x2 > 0.0f) ? x2 : 0.2f * x2;
    const float C  = 0.5f * (__expf(x1) + __expf(x2));   // symmetric g <-> rev[g]
    const float js = Jv / C;
    p.edgeP[g] = make_int4(j, rg, __float_as_int(js), __float_as_int(C));

    float sc = C;
    sc += __shfl_xor(sc, 1); sc += __shfl_xor(sc, 2);
    sc += __shfl_xor(sc, 4); sc += __shfl_xor(sc, 8);
    const float s  = ci + sc;
    const float cl = fmaxf(fabsf(s), 0.1f);
    const float d  = (s > 0.0f) ? cl : ((s < 0.0f) ? -cl : 0.0f);
    const float rd = 1.0f / d;
    const float bs = bi * rd;
    if (t == 0) {
        p.dom_out[i] = d;
        p.uA[i] = make_float2(-bs, bs);       // u0 = bx_scale (em0 = 0)
    }
    grid_bar(p.bar, 1);                       // (2) uA, edgeP visible

    // prefetch epilogue operands (independent of BP steps)
    int eE = 0, eR = 0, eC = 0, eEr = 0;
    float jse = 0.0f, Ce = 0.0f;
    if (g < p.Eu) {
        eE = p.u2e[g]; eR = p.ru[g]; eC = p.cu[g];
        const int4 ep = p.edgeP[eE];
        eEr = ep.y; jse = __int_as_float(ep.z); Ce = __int_as_float(ep.w);
    }

    // ---------------- BP steps (all state in registers) ---------------------
    float2 *uP = p.uA, *uQ = p.uB, *emP = p.emA, *emQ = p.emB;
    for (int st = 0; st < NSTEP; ++st) {
        const float2 uj = uP[j];              // two independent 8B gathers
        const float2 mu = emP[rg];
        const float a0 = uj.x - mu.x, a1 = uj.y - mu.y;
        const float t0 = fmaxf( js + a0, -js + a1);
        const float t1 = fmaxf(-js + a0,  js + a1);
        const float ls = lse2(t0, t1);
        const float e0 = C * (t0 - ls), e1 = C * (t1 - ls);
        emQ[g] = make_float2(e0, e1);

        float nm0 = e0, nm1 = e1;             // node's 16 incoming messages
        nm0 += __shfl_xor(nm0, 1); nm1 += __shfl_xor(nm1, 1);
        nm0 += __shfl_xor(nm0, 2); nm1 += __shfl_xor(nm1, 2);
        nm0 += __shfl_xor(nm0, 4); nm1 += __shfl_xor(nm1, 4);
        nm0 += __shfl_xor(nm0, 8); nm1 += __shfl_xor(nm1, 8);
        const float v0 = -bs + nm0 * rd, v1 = bs + nm1 * rd;
        if (t == 0) uQ[i] = make_float2(v0, v1);

        if (st == NSTEP - 1) {                // node readout + node entropy
            float nodeC = 0.0f;
            if (t == 0) {
                const float lz = lse2(v0, v1);
                const float r0 = __expf(v0 - lz), r1 = __expf(v1 - lz);
                p.ro_out[i] = make_float2(r0, r1);
                const float H = -(r0 * __logf(r0 + 1e-16f) + r1 * __logf(r1 + 1e-16f));
                nodeC = ci * H;
            }
            for (int off = 32; off > 0; off >>= 1) nodeC += __shfl_down(nodeC, off);
            const int wv = tidb >> 6;
            if (lane == 0) red[wv] = nodeC;
            __syncthreads();
            if (tidb == 0) {
                float sn = 0.0f;
                #pragma unroll
                for (int w = 0; w < TB / 64; ++w) sn += red[w];
                atomicAdd(&p.ent[0], sn);
                atomicAdd(&p.ent[1], sn);
            }
        }
        grid_bar(p.bar, 2 + st);              // step st results visible
        float2* tp;
        tp = uP;  uP  = uQ;  uQ  = tp;
        tp = emP; emP = emQ; emQ = tp;
    }
    // uP/emP now hold final values

    // ---------------- epilogue: pairwise readout + edge entropy -------------
    float edgeC = 0.0f;
    if (g < p.Eu) {
        const float2 uc = uP[eC], ur = uP[eR];
        const float lc = lse2(uc.x, uc.y);
        const float lr = lse2(ur.x, ur.y);
        const float2 eme = emP[eEr];          // message on edge e at slot rev[e]
        const float2 emr = emP[eE];           // message on rev[e] at slot e
        const float ti0 = (uc.x - lc) - eme.x, ti1 = (uc.y - lc) - eme.y;
        const float tj0 = (ur.x - lr) - emr.x, tj1 = (ur.y - lr) - emr.y;
        const float L00 =  jse + ti0 + tj0;
        const float L01 = -jse + ti1 + tj0;
        const float L10 = -jse + ti0 + tj1;
        const float L11 =  jse + ti1 + tj1;
        const float mL = fmaxf(fmaxf(L00, L01), fmaxf(L10, L11));
        float p00 = __expf(L00 - mL), p01 = __expf(L01 - mL);
        float p10 = __expf(L10 - mL), p11 = __expf(L11 - mL);
        const float inv = 1.0f / (p00 + p01 + p10 + p11);
        p00 *= inv; p01 *= inv; p10 *= inv; p11 *= inv;
        p.rp_out[g] = make_float4(p00, p01, p10, p11);
        p.cij_out[g] = Ce;
        const float H = -(p00 * __logf(p00 + 1e-16f) + p01 * __logf(p01 + 1e-16f)
                        + p10 * __logf(p10 + 1e-16f) + p11 * __logf(p11 + 1e-16f));
        edgeC = Ce * H;
    }
    for (int off = 32; off > 0; off >>= 1) edgeC += __shfl_down(edgeC, off);
    const int wv = tidb >> 6;
    if (lane == 0) red[wv] = edgeC;
    __syncthreads();
    if (tidb == 0) {
        float se = 0.0f;
        #pragma unroll
        for (int w = 0; w < TB / 64; ++w) se += red[w];
        atomicAdd(&p.ent[0], se);
        atomicAdd(&p.ent[2], se);
    }
}

extern "C" void kernel_launch(void* const* d_in, const int* in_sizes, int n_in,
                              void* d_out, int out_size, void* d_ws, size_t ws_size,
                              hipStream_t stream) {
    const int N  = in_sizes[1];
    const int E  = in_sizes[10];
    const int Eu = in_sizes[13];

    float* out = (float*)d_out;
    size_t OFF_RP  = 2 * (size_t)N;
    size_t OFF_ENT = OFF_RP + 4 * (size_t)Eu;

    char* w = (char*)d_ws;
    auto carve = [&](size_t bytes) {
        void* q = (void*)w;
        w += (bytes + 255) & ~(size_t)255;
        return q;
    };

    KParams p;
    p.J     = (const float*)d_in[0];
    p.bias  = (const float*)d_in[1];
    p.gat_W = (const float*)d_in[2];
    p.gat_a = (const float*)d_in[3];
    p.W1    = (const float*)d_in[4];
    p.b1    = (const float*)d_in[5];
    p.W2    = (const float*)d_in[6];
    p.b2    = (const float*)d_in[7];
    p.W3    = (const float*)d_in[8];
    p.b3    = (const float*)d_in[9];
    p.col   = (const int*)d_in[11];
    p.rev   = (const int*)d_in[12];
    p.ru    = (const int*)d_in[13];
    p.cu    = (const int*)d_in[14];
    p.u2e   = (const int*)d_in[15];
    p.N = N; p.Eu = Eu;

    p.edgeP = (int4*)carve((size_t)E * 16);
    p.fA    = (float2*)carve((size_t)N * 8);
    p.uA    = (float2*)carve((size_t)N * 8);
    p.uB    = (float2*)carve((size_t)N * 8);
    p.emA   = (float2*)carve((size_t)E * 8);
    p.emB   = (float2*)carve((size_t)E * 8);
    p.bar   = (int*)carve(16 * 128);          // 16 barrier counters, 128B apart

    p.ro_out  = (float2*)out;
    p.rp_out  = (float4*)(out + OFF_RP);
    p.ent     = out + OFF_ENT;
    p.ci_out  = p.ent + 3;
    p.cij_out = p.ci_out + N;
    p.dom_out = p.cij_out + Eu;

    hipMemsetAsync(p.bar, 0, 16 * 128, stream);
    k_fused<<<dim3(NB), dim3(TB), 0, stream>>>(p);
}

// Round 3
// 185.113 us; speedup vs baseline: 1.8676x; 1.1475x over previous
//
#include <hip/hip_runtime.h>
#include <cstddef>

#define TB    1024
#define NB    64
#define NSTEP 10
// Problem constants: N=4096, E=65536 (=N*16, uniform degree 16, row-major
// sorted so out-edges of node i are slots [16i,16i+16)), Eu=32768.
// Slot scheme: em buffer slot g (g=16i+t) holds the message on edge
// rev[g]=(j->i), so node i's incoming messages are slots [16i,16i+16).
// We propagate u = hidden + lnZ; hidden recovered as u - lse(u) at readout.
// R9: fenceless grid barrier. R8's barrier cost ~8us each because
// __threadfence() at agent scope = buffer_wbl2/buffer_inv (full L2 flush).
// Fix: all cross-block data uses agent-scope RELAXED atomic load/store
// (write-through, cache-bypassing) -> barrier needs NO cache maintenance:
// __syncthreads (drains vmcnt) -> relaxed fetch_add -> relaxed poll.
// edgeP eliminated (step loop uses own registers; epilogue reads jsC + input
// rev[]). ent zero-init via agent store (plain store would race atomicAdd).

__device__ __forceinline__ float lse2(float a, float b) {
    return fmaxf(a, b) + __logf(1.0f + __expf(-fabsf(a - b)));
}

// agent-scope write-through / cache-bypass 8B accessors
__device__ __forceinline__ void stA(float2* p, float2 v) {
    union { float2 f; unsigned long long u; } x; x.f = v;
    __hip_atomic_store((unsigned long long*)p, x.u,
                       __ATOMIC_RELAXED, __HIP_MEMORY_SCOPE_AGENT);
}
__device__ __forceinline__ float2 ldA(const float2* p) {
    union { float2 f; unsigned long long u; } x;
    x.u = __hip_atomic_load((const unsigned long long*)p,
                            __ATOMIC_RELAXED, __HIP_MEMORY_SCOPE_AGENT);
    return x.f;
}

struct KParams {
    const float *J, *bias, *gat_W, *gat_a, *W1, *b1, *W2, *b2, *W3, *b3;
    const int *col, *rev, *ru, *cu, *u2e;
    int N, Eu;
    float2 *jsC, *fA, *uA, *uB, *emA, *emB;
    int*    bar;                 // 16 counters, 128B apart, pre-zeroed
    float  *ci_out, *dom_out, *ent;
    float2* ro_out;
    float4* rp_out;
    float*  cij_out;
};

// Fenceless centralized grid barrier. __syncthreads() makes every wave drain
// its vmem (s_waitcnt vmcnt(0) before s_barrier), so all this block's
// write-through stores are at the coherence point before thread 0 arrives.
__device__ __forceinline__ void grid_bar(int* bar, int idx) {
    __syncthreads();
    if (threadIdx.x == 0) {
        int* c = &bar[idx * 32];
        __hip_atomic_fetch_add(c, 1, __ATOMIC_RELAXED, __HIP_MEMORY_SCOPE_AGENT);
        while (__hip_atomic_load(c, __ATOMIC_RELAXED,
                                 __HIP_MEMORY_SCOPE_AGENT) < NB) {}
    }
    __syncthreads();
}

__global__ __launch_bounds__(TB) void k_fused(KParams p) {
    __shared__ float sW2[64 * 64];
    __shared__ float sh1[TB / 16][65];
    __shared__ float red[TB / 64];

    const int tidb = threadIdx.x;
    const int g = blockIdx.x * TB + tidb;
    const int i = g >> 4, t = g & 15;
    const int lane = tidb & 63;

    // ---------------- phase A: per-node quantities --------------------------
    for (int k = tidb; k < 64 * 64; k += TB) sW2[k] = p.W2[k];
    if (g < 3) {  // agent-scope store: must reach MALL before later atomicAdds
        __hip_atomic_store((int*)&p.ent[g], 0,
                           __ATOMIC_RELAXED, __HIP_MEMORY_SCOPE_AGENT);
    }
    stA(&p.emA[g], make_float2(0.0f, 0.0f));  // em0 = log(1) = 0

    const int j  = p.col[g];
    const int rg = p.rev[g];
    const float Jv = p.J[(size_t)i * (size_t)p.N + (size_t)j];

    float rs = Jv;                            // row-sum of node i (16 nnz)
    rs += __shfl_xor(rs, 1); rs += __shfl_xor(rs, 2);
    rs += __shfl_xor(rs, 4); rs += __shfl_xor(rs, 8);

    const float bi = p.bias[i];

    float s8 = 0.0f;                          // gat_W^T @ gat_a halves
    if (lane < 8) {
        int k = lane & 3;
        const float* a = p.gat_a + ((lane < 4) ? 0 : 64);
        for (int h = 0; h < 64; ++h) s8 += p.gat_W[k * 64 + h] * a[h];
    }
    const float w10 = __shfl(s8, 0), w11 = __shfl(s8, 1), w12 = __shfl(s8, 2), w13 = __shfl(s8, 3);
    const float w20 = __shfl(s8, 4), w21 = __shfl(s8, 5), w22 = __shfl(s8, 6), w23 = __shfl(s8, 7);
    const float fd = 16.0f;
    const float f1i = -bi * w10 + bi * w11 + fd * w12 + rs * w13;
    const float f2i = -bi * w20 + bi * w21 + fd * w22 + rs * w23;

    // Ci readout MLP (per node, 16 threads per node)
    const int nib = tidb >> 4;
    __syncthreads();                          // sW2 staged
    #pragma unroll
    for (int m = 0; m < 4; ++m) {
        int h = t + 16 * m;
        float a = -bi * p.W1[h] + bi * p.W1[64 + h] + fd * p.W1[128 + h]
                + rs * p.W1[192 + h] + p.b1[h];
        sh1[nib][h] = fmaxf(a, 0.0f);
    }
    __syncthreads();
    float civ = 0.0f;
    #pragma unroll
    for (int m = 0; m < 4; ++m) {
        int o = t + 16 * m;
        float acc = p.b2[o];
        for (int h = 0; h < 64; ++h) acc += sh1[nib][h] * sW2[h * 64 + o];
        civ += fmaxf(acc, 0.0f) * p.W3[o];
    }
    civ += __shfl_xor(civ, 1); civ += __shfl_xor(civ, 2);
    civ += __shfl_xor(civ, 4); civ += __shfl_xor(civ, 8);
    const float ci = civ + p.b3[0];

    if (t == 0) {
        stA(&p.fA[i], make_float2(f1i, f2i));
        p.ci_out[i] = ci;                     // output only, plain store
    }
    grid_bar(p.bar, 0);                       // (1) fA, em0 visible

    // ---------------- phase B: per-edge params + dom ------------------------
    const float2 fj = ldA(&p.fA[j]);          // f1/f2 of neighbor (1 load)
    float x1 = f1i + fj.y; x1 = (x1 > 0.0f) ? x1 : 0.2f * x1;
    float x2 = fj.x + f2i; x2 = (x2 > 0.0f) ? x2 : 0.2f * x2;
    const float C  = 0.5f * (__expf(x1) + __expf(x2));   // symmetric g <-> rev[g]
    const float js = Jv / C;
    stA(&p.jsC[g], make_float2(js, C));       // for epilogue (foreign reads)

    float sc = C;
    sc += __shfl_xor(sc, 1); sc += __shfl_xor(sc, 2);
    sc += __shfl_xor(sc, 4); sc += __shfl_xor(sc, 8);
    const float s  = ci + sc;
    const float cl = fmaxf(fabsf(s), 0.1f);
    const float d  = (s > 0.0f) ? cl : ((s < 0.0f) ? -cl : 0.0f);
    const float rd = 1.0f / d;
    const float bs = bi * rd;
    if (t == 0) {
        p.dom_out[i] = d;                     // output only
        stA(&p.uA[i], make_float2(-bs, bs));  // u0 = bx_scale (em0 = 0)
    }
    grid_bar(p.bar, 1);                       // (2) uA, jsC visible

    // prefetch epilogue operands (independent of BP steps)
    int eE = 0, eR = 0, eC = 0, eEr = 0;
    float jse = 0.0f, Ce = 0.0f;
    if (g < p.Eu) {
        eE = p.u2e[g]; eR = p.ru[g]; eC = p.cu[g];
        eEr = p.rev[eE];                      // read-only input array
        const float2 jc = ldA(&p.jsC[eE]);
        jse = jc.x; Ce = jc.y;
    }

    // ---------------- BP steps (all state in registers) ---------------------
    float2 *uP = p.uA, *uQ = p.uB, *emP = p.emA, *emQ = p.emB;
    for (int st = 0; st < NSTEP; ++st) {
        const float2 uj = ldA(&uP[j]);        // two independent 8B gathers
        const float2 mu = ldA(&emP[rg]);
        const float a0 = uj.x - mu.x, a1 = uj.y - mu.y;
        const float t0 = fmaxf( js + a0, -js + a1);
        const float t1 = fmaxf(-js + a0,  js + a1);
        const float ls = lse2(t0, t1);
        const float e0 = C * (t0 - ls), e1 = C * (t1 - ls);
        stA(&emQ[g], make_float2(e0, e1));

        float nm0 = e0, nm1 = e1;             // node's 16 incoming messages
        nm0 += __shfl_xor(nm0, 1); nm1 += __shfl_xor(nm1, 1);
        nm0 += __shfl_xor(nm0, 2); nm1 += __shfl_xor(nm1, 2);
        nm0 += __shfl_xor(nm0, 4); nm1 += __shfl_xor(nm1, 4);
        nm0 += __shfl_xor(nm0, 8); nm1 += __shfl_xor(nm1, 8);
        const float v0 = -bs + nm0 * rd, v1 = bs + nm1 * rd;
        if (t == 0) stA(&uQ[i], make_float2(v0, v1));

        if (st == NSTEP - 1) {                // node readout + node entropy
            float nodeC = 0.0f;
            if (t == 0) {
                const float lz = lse2(v0, v1);
                const float r0 = __expf(v0 - lz), r1 = __expf(v1 - lz);
                p.ro_out[i] = make_float2(r0, r1);
                const float H = -(r0 * __logf(r0 + 1e-16f) + r1 * __logf(r1 + 1e-16f));
                nodeC = ci * H;
            }
            for (int off = 32; off > 0; off >>= 1) nodeC += __shfl_down(nodeC, off);
            const int wv = tidb >> 6;
            if (lane == 0) red[wv] = nodeC;
            __syncthreads();
            if (tidb == 0) {
                float sn = 0.0f;
                #pragma unroll
                for (int w = 0; w < TB / 64; ++w) sn += red[w];
                atomicAdd(&p.ent[0], sn);
                atomicAdd(&p.ent[1], sn);
            }
        }
        grid_bar(p.bar, 2 + st);              // step st results visible
        float2* tp;
        tp = uP;  uP  = uQ;  uQ  = tp;
        tp = emP; emP = emQ; emQ = tp;
    }
    // uP/emP now hold final values

    // ---------------- epilogue: pairwise readout + edge entropy -------------
    float edgeC = 0.0f;
    if (g < p.Eu) {
        const float2 uc = ldA(&uP[eC]), ur = ldA(&uP[eR]);
        const float lc = lse2(uc.x, uc.y);
        const float lr = lse2(ur.x, ur.y);
        const float2 eme = ldA(&emP[eEr]);    // message on edge e at slot rev[e]
        const float2 emr = ldA(&emP[eE]);     // message on rev[e] at slot e
        const float ti0 = (uc.x - lc) - eme.x, ti1 = (uc.y - lc) - eme.y;
        const float tj0 = (ur.x - lr) - emr.x, tj1 = (ur.y - lr) - emr.y;
        const float L00 =  jse + ti0 + tj0;
        const float L01 = -jse + ti1 + tj0;
        const float L10 = -jse + ti0 + tj1;
        const float L11 =  jse + ti1 + tj1;
        const float mL = fmaxf(fmaxf(L00, L01), fmaxf(L10, L11));
        float p00 = __expf(L00 - mL), p01 = __expf(L01 - mL);
        float p10 = __expf(L10 - mL), p11 = __expf(L11 - mL);
        const float inv = 1.0f / (p00 + p01 + p10 + p11);
        p00 *= inv; p01 *= inv; p10 *= inv; p11 *= inv;
        p.rp_out[g] = make_float4(p00, p01, p10, p11);
        p.cij_out[g] = Ce;
        const float H = -(p00 * __logf(p00 + 1e-16f) + p01 * __logf(p01 + 1e-16f)
                        + p10 * __logf(p10 + 1e-16f) + p11 * __logf(p11 + 1e-16f));
        edgeC = Ce * H;
    }
    for (int off = 32; off > 0; off >>= 1) edgeC += __shfl_down(edgeC, off);
    const int wv = tidb >> 6;
    if (lane == 0) red[wv] = edgeC;
    __syncthreads();
    if (tidb == 0) {
        float se = 0.0f;
        #pragma unroll
        for (int w = 0; w < TB / 64; ++w) se += red[w];
        atomicAdd(&p.ent[0], se);
        atomicAdd(&p.ent[2], se);
    }
}

extern "C" void kernel_launch(void* const* d_in, const int* in_sizes, int n_in,
                              void* d_out, int out_size, void* d_ws, size_t ws_size,
                              hipStream_t stream) {
    const int N  = in_sizes[1];
    const int E  = in_sizes[10];
    const int Eu = in_sizes[13];

    float* out = (float*)d_out;
    size_t OFF_RP  = 2 * (size_t)N;
    size_t OFF_ENT = OFF_RP + 4 * (size_t)Eu;

    char* w = (char*)d_ws;
    auto carve = [&](size_t bytes) {
        void* q = (void*)w;
        w += (bytes + 255) & ~(size_t)255;
        return q;
    };

    KParams p;
    p.J     = (const float*)d_in[0];
    p.bias  = (const float*)d_in[1];
    p.gat_W = (const float*)d_in[2];
    p.gat_a = (const float*)d_in[3];
    p.W1    = (const float*)d_in[4];
    p.b1    = (const float*)d_in[5];
    p.W2    = (const float*)d_in[6];
    p.b2    = (const float*)d_in[7];
    p.W3    = (const float*)d_in[8];
    p.b3    = (const float*)d_in[9];
    p.col   = (const int*)d_in[11];
    p.rev   = (const int*)d_in[12];
    p.ru    = (const int*)d_in[13];
    p.cu    = (const int*)d_in[14];
    p.u2e   = (const int*)d_in[15];
    p.N = N; p.Eu = Eu;

    p.jsC   = (float2*)carve((size_t)E * 8);
    p.fA    = (float2*)carve((size_t)N * 8);
    p.uA    = (float2*)carve((size_t)N * 8);
    p.uB    = (float2*)carve((size_t)N * 8);
    p.emA   = (float2*)carve((size_t)E * 8);
    p.emB   = (float2*)carve((size_t)E * 8);
    p.bar   = (int*)carve(16 * 128);          // 16 barrier counters, 128B apart

    p.ro_out  = (float2*)out;
    p.rp_out  = (float4*)(out + OFF_RP);
    p.ent     = out + OFF_ENT;
    p.ci_out  = p.ent + 3;
    p.cij_out = p.ci_out + N;
    p.dom_out = p.cij_out + Eu;

    hipMemsetAsync(p.bar, 0, 16 * 128, stream);
    k_fused<<<dim3(NB), dim3(TB), 0, stream>>>(p);
}

// Round 4
// 162.961 us; speedup vs baseline: 2.1215x; 1.1359x over previous
//
#include <hip/hip_runtime.h>
#include <cstddef>

#define TB    512
#define NB    128
#define NSTEP 10
// Problem constants: N=4096, E=65536 (=N*16, uniform degree 16, row-major
// sorted so out-edges of node i are slots [16i,16i+16)), Eu=32768.
// Slot scheme: em buffer slot g (g=16i+t) holds the message on edge
// rev[g]=(j->i), so node i's incoming messages are slots [16i,16i+16).
// We propagate u = hidden + lnZ; hidden recovered as u - lse(u) at readout.
// R10: distributed-flag grid barrier. R9's centralized counter serialized 64
// atomic RMWs on one MALL line (~4-5us/barrier). Now block b STORES ordinal
// to its own cacheline flags[b*32]; threads 0..NB-1 poll one flag each with
// relaxed agent loads. Arrivals are contention-free; barrier ~= one MALL
// store + one poll round-trip. Grid 64x1024 -> 128x512 (2x CUs for compute
// phases; barrier cost no longer scales with block count).
// All cross-block data stays agent-scope relaxed atomic ld/st (cache-bypass,
// write-through) so no cache-maintenance fences are ever needed; the
// compiler-emitted s_waitcnt vmcnt(0) before s_barrier drains stores to the
// coherence point before the arrival flag is raised.

__device__ __forceinline__ float lse2(float a, float b) {
    return fmaxf(a, b) + __logf(1.0f + __expf(-fabsf(a - b)));
}

// agent-scope write-through / cache-bypass 8B accessors
__device__ __forceinline__ void stA(float2* p, float2 v) {
    union { float2 f; unsigned long long u; } x; x.f = v;
    __hip_atomic_store((unsigned long long*)p, x.u,
                       __ATOMIC_RELAXED, __HIP_MEMORY_SCOPE_AGENT);
}
__device__ __forceinline__ float2 ldA(const float2* p) {
    union { float2 f; unsigned long long u; } x;
    x.u = __hip_atomic_load((const unsigned long long*)p,
                            __ATOMIC_RELAXED, __HIP_MEMORY_SCOPE_AGENT);
    return x.f;
}

struct KParams {
    const float *J, *bias, *gat_W, *gat_a, *W1, *b1, *W2, *b2, *W3, *b3;
    const int *col, *rev, *ru, *cu, *u2e;
    int N, Eu;
    float2 *jsC, *fA, *uA, *uB, *emA, *emB;
    int*    bar;                 // NB flags, 128B apart, pre-zeroed
    float  *ci_out, *dom_out, *ent;
    float2* ro_out;
    float4* rp_out;
    float*  cij_out;
};

// Distributed-flag grid barrier (no RMW, no fences). Monotone ordinals.
__device__ __forceinline__ void grid_bar(int* flags, int expect) {
    __syncthreads();                          // drains all waves' vmem stores
    if (threadIdx.x == 0)
        __hip_atomic_store(&flags[blockIdx.x * 32], expect,
                           __ATOMIC_RELAXED, __HIP_MEMORY_SCOPE_AGENT);
    if (threadIdx.x < NB) {
        while (__hip_atomic_load(&flags[threadIdx.x * 32], __ATOMIC_RELAXED,
                                 __HIP_MEMORY_SCOPE_AGENT) < expect) {}
    }
    __syncthreads();
}

__global__ __launch_bounds__(TB) void k_fused(KParams p) {
    __shared__ float sW2[64 * 64];
    __shared__ float sh1[TB / 16][65];
    __shared__ float red[TB / 64];

    const int tidb = threadIdx.x;
    const int g = blockIdx.x * TB + tidb;
    const int i = g >> 4, t = g & 15;
    const int lane = tidb & 63;

    // ---------------- phase A: per-node quantities --------------------------
    for (int k = tidb; k < 64 * 64; k += TB) sW2[k] = p.W2[k];
    if (g < 3) {  // agent-scope store: must reach MALL before later atomicAdds
        __hip_atomic_store((int*)&p.ent[g], 0,
                           __ATOMIC_RELAXED, __HIP_MEMORY_SCOPE_AGENT);
    }
    stA(&p.emA[g], make_float2(0.0f, 0.0f));  // em0 = log(1) = 0

    const int j  = p.col[g];
    const int rg = p.rev[g];
    const float Jv = p.J[(size_t)i * (size_t)p.N + (size_t)j];

    float rs = Jv;                            // row-sum of node i (16 nnz)
    rs += __shfl_xor(rs, 1); rs += __shfl_xor(rs, 2);
    rs += __shfl_xor(rs, 4); rs += __shfl_xor(rs, 8);

    const float bi = p.bias[i];

    float s8 = 0.0f;                          // gat_W^T @ gat_a halves
    if (lane < 8) {
        int k = lane & 3;
        const float* a = p.gat_a + ((lane < 4) ? 0 : 64);
        for (int h = 0; h < 64; ++h) s8 += p.gat_W[k * 64 + h] * a[h];
    }
    const float w10 = __shfl(s8, 0), w11 = __shfl(s8, 1), w12 = __shfl(s8, 2), w13 = __shfl(s8, 3);
    const float w20 = __shfl(s8, 4), w21 = __shfl(s8, 5), w22 = __shfl(s8, 6), w23 = __shfl(s8, 7);
    const float fd = 16.0f;
    const float f1i = -bi * w10 + bi * w11 + fd * w12 + rs * w13;
    const float f2i = -bi * w20 + bi * w21 + fd * w22 + rs * w23;

    // Ci readout MLP (per node, 16 threads per node)
    const int nib = tidb >> 4;
    __syncthreads();                          // sW2 staged
    #pragma unroll
    for (int m = 0; m < 4; ++m) {
        int h = t + 16 * m;
        float a = -bi * p.W1[h] + bi * p.W1[64 + h] + fd * p.W1[128 + h]
                + rs * p.W1[192 + h] + p.b1[h];
        sh1[nib][h] = fmaxf(a, 0.0f);
    }
    __syncthreads();
    float civ = 0.0f;
    #pragma unroll
    for (int m = 0; m < 4; ++m) {
        int o = t + 16 * m;
        float acc = p.b2[o];
        for (int h = 0; h < 64; ++h) acc += sh1[nib][h] * sW2[h * 64 + o];
        civ += fmaxf(acc, 0.0f) * p.W3[o];
    }
    civ += __shfl_xor(civ, 1); civ += __shfl_xor(civ, 2);
    civ += __shfl_xor(civ, 4); civ += __shfl_xor(civ, 8);
    const float ci = civ + p.b3[0];

    if (t == 0) {
        stA(&p.fA[i], make_float2(f1i, f2i));
        p.ci_out[i] = ci;                     // output only, plain store
    }
    grid_bar(p.bar, 1);                       // (1) fA, em0 visible

    // ---------------- phase B: per-edge params + dom ------------------------
    const float2 fj = ldA(&p.fA[j]);          // f1/f2 of neighbor (1 load)
    float x1 = f1i + fj.y; x1 = (x1 > 0.0f) ? x1 : 0.2f * x1;
    float x2 = fj.x + f2i; x2 = (x2 > 0.0f) ? x2 : 0.2f * x2;
    const float C  = 0.5f * (__expf(x1) + __expf(x2));   // symmetric g <-> rev[g]
    const float js = Jv / C;
    stA(&p.jsC[g], make_float2(js, C));       // for epilogue (foreign reads)

    float sc = C;
    sc += __shfl_xor(sc, 1); sc += __shfl_xor(sc, 2);
    sc += __shfl_xor(sc, 4); sc += __shfl_xor(sc, 8);
    const float s  = ci + sc;
    const float cl = fmaxf(fabsf(s), 0.1f);
    const float d  = (s > 0.0f) ? cl : ((s < 0.0f) ? -cl : 0.0f);
    const float rd = 1.0f / d;
    const float bs = bi * rd;
    if (t == 0) {
        p.dom_out[i] = d;                     // output only
        stA(&p.uA[i], make_float2(-bs, bs));  // u0 = bx_scale (em0 = 0)
    }
    grid_bar(p.bar, 2);                       // (2) uA, jsC visible

    // prefetch epilogue operands (independent of BP steps)
    int eE = 0, eR = 0, eC = 0, eEr = 0;
    float jse = 0.0f, Ce = 0.0f;
    if (g < p.Eu) {
        eE = p.u2e[g]; eR = p.ru[g]; eC = p.cu[g];
        eEr = p.rev[eE];                      // read-only input array
        const float2 jc = ldA(&p.jsC[eE]);
        jse = jc.x; Ce = jc.y;
    }

    // ---------------- BP steps (all state in registers) ---------------------
    float2 *uP = p.uA, *uQ = p.uB, *emP = p.emA, *emQ = p.emB;
    for (int st = 0; st < NSTEP; ++st) {
        const float2 uj = ldA(&uP[j]);        // two independent 8B gathers
        const float2 mu = ldA(&emP[rg]);
        const float a0 = uj.x - mu.x, a1 = uj.y - mu.y;
        const float t0 = fmaxf( js + a0, -js + a1);
        const float t1 = fmaxf(-js + a0,  js + a1);
        const float ls = lse2(t0, t1);
        const float e0 = C * (t0 - ls), e1 = C * (t1 - ls);
        stA(&emQ[g], make_float2(e0, e1));

        float nm0 = e0, nm1 = e1;             // node's 16 incoming messages
        nm0 += __shfl_xor(nm0, 1); nm1 += __shfl_xor(nm1, 1);
        nm0 += __shfl_xor(nm0, 2); nm1 += __shfl_xor(nm1, 2);
        nm0 += __shfl_xor(nm0, 4); nm1 += __shfl_xor(nm1, 4);
        nm0 += __shfl_xor(nm0, 8); nm1 += __shfl_xor(nm1, 8);
        const float v0 = -bs + nm0 * rd, v1 = bs + nm1 * rd;
        if (t == 0) stA(&uQ[i], make_float2(v0, v1));

        if (st == NSTEP - 1) {                // node readout + node entropy
            float nodeC = 0.0f;
            if (t == 0) {
                const float lz = lse2(v0, v1);
                const float r0 = __expf(v0 - lz), r1 = __expf(v1 - lz);
                p.ro_out[i] = make_float2(r0, r1);
                const float H = -(r0 * __logf(r0 + 1e-16f) + r1 * __logf(r1 + 1e-16f));
                nodeC = ci * H;
            }
            for (int off = 32; off > 0; off >>= 1) nodeC += __shfl_down(nodeC, off);
            const int wv = tidb >> 6;
            if (lane == 0) red[wv] = nodeC;
            __syncthreads();
            if (tidb == 0) {
                float sn = 0.0f;
                #pragma unroll
                for (int w = 0; w < TB / 64; ++w) sn += red[w];
                atomicAdd(&p.ent[0], sn);
                atomicAdd(&p.ent[1], sn);
            }
        }
        grid_bar(p.bar, 3 + st);              // step st results visible
        float2* tp;
        tp = uP;  uP  = uQ;  uQ  = tp;
        tp = emP; emP = emQ; emQ = tp;
    }
    // uP/emP now hold final values

    // ---------------- epilogue: pairwise readout + edge entropy -------------
    float edgeC = 0.0f;
    if (g < p.Eu) {
        const float2 uc = ldA(&uP[eC]), ur = ldA(&uP[eR]);
        const float lc = lse2(uc.x, uc.y);
        const float lr = lse2(ur.x, ur.y);
        const float2 eme = ldA(&emP[eEr]);    // message on edge e at slot rev[e]
        const float2 emr = ldA(&emP[eE]);     // message on rev[e] at slot e
        const float ti0 = (uc.x - lc) - eme.x, ti1 = (uc.y - lc) - eme.y;
        const float tj0 = (ur.x - lr) - emr.x, tj1 = (ur.y - lr) - emr.y;
        const float L00 =  jse + ti0 + tj0;
        const float L01 = -jse + ti1 + tj0;
        const float L10 = -jse + ti0 + tj1;
        const float L11 =  jse + ti1 + tj1;
        const float mL = fmaxf(fmaxf(L00, L01), fmaxf(L10, L11));
        float p00 = __expf(L00 - mL), p01 = __expf(L01 - mL);
        float p10 = __expf(L10 - mL), p11 = __expf(L11 - mL);
        const float inv = 1.0f / (p00 + p01 + p10 + p11);
        p00 *= inv; p01 *= inv; p10 *= inv; p11 *= inv;
        p.rp_out[g] = make_float4(p00, p01, p10, p11);
        p.cij_out[g] = Ce;
        const float H = -(p00 * __logf(p00 + 1e-16f) + p01 * __logf(p01 + 1e-16f)
                        + p10 * __logf(p10 + 1e-16f) + p11 * __logf(p11 + 1e-16f));
        edgeC = Ce * H;
    }
    for (int off = 32; off > 0; off >>= 1) edgeC += __shfl_down(edgeC, off);
    const int wv = tidb >> 6;
    if (lane == 0) red[wv] = edgeC;
    __syncthreads();
    if (tidb == 0) {
        float se = 0.0f;
        #pragma unroll
        for (int w = 0; w < TB / 64; ++w) se += red[w];
        atomicAdd(&p.ent[0], se);
        atomicAdd(&p.ent[2], se);
    }
}

extern "C" void kernel_launch(void* const* d_in, const int* in_sizes, int n_in,
                              void* d_out, int out_size, void* d_ws, size_t ws_size,
                              hipStream_t stream) {
    const int N  = in_sizes[1];
    const int E  = in_sizes[10];
    const int Eu = in_sizes[13];

    float* out = (float*)d_out;
    size_t OFF_RP  = 2 * (size_t)N;
    size_t OFF_ENT = OFF_RP + 4 * (size_t)Eu;

    char* w = (char*)d_ws;
    auto carve = [&](size_t bytes) {
        void* q = (void*)w;
        w += (bytes + 255) & ~(size_t)255;
        return q;
    };

    KParams p;
    p.J     = (const float*)d_in[0];
    p.bias  = (const float*)d_in[1];
    p.gat_W = (const float*)d_in[2];
    p.gat_a = (const float*)d_in[3];
    p.W1    = (const float*)d_in[4];
    p.b1    = (const float*)d_in[5];
    p.W2    = (const float*)d_in[6];
    p.b2    = (const float*)d_in[7];
    p.W3    = (const float*)d_in[8];
    p.b3    = (const float*)d_in[9];
    p.col   = (const int*)d_in[11];
    p.rev   = (const int*)d_in[12];
    p.ru    = (const int*)d_in[13];
    p.cu    = (const int*)d_in[14];
    p.u2e   = (const int*)d_in[15];
    p.N = N; p.Eu = Eu;

    p.jsC   = (float2*)carve((size_t)E * 8);
    p.fA    = (float2*)carve((size_t)N * 8);
    p.uA    = (float2*)carve((size_t)N * 8);
    p.uB    = (float2*)carve((size_t)N * 8);
    p.emA   = (float2*)carve((size_t)E * 8);
    p.emB   = (float2*)carve((size_t)E * 8);
    p.bar   = (int*)carve((size_t)NB * 128);  // NB flags, 128B apart

    p.ro_out  = (float2*)out;
    p.rp_out  = (float4*)(out + OFF_RP);
    p.ent     = out + OFF_ENT;
    p.ci_out  = p.ent + 3;
    p.cij_out = p.ci_out + N;
    p.dom_out = p.cij_out + Eu;

    hipMemsetAsync(p.bar, 0, (size_t)NB * 128, stream);
    k_fused<<<dim3(NB), dim3(TB), 0, stream>>>(p);
}

// Round 5
// 160.407 us; speedup vs baseline: 2.1552x; 1.0159x over previous
//
#include <hip/hip_runtime.h>
#include <cstddef>

#define TB    512
#define NB    128
#define NSTEP 10
// Problem constants: N=4096, E=65536 (=N*16, uniform degree 16, row-major
// sorted so out-edges of node i are slots [16i,16i+16)), Eu=32768.
// Slot scheme: em slot g (g=16i+t) holds the message on edge rev[g]=(j->i),
// so node i's incoming messages are slots [16i,16i+16).
// We propagate u = hidden + lnZ; hidden recovered as u - lse(u) at readout.
// R11: (a) BOTH directed messages of the undirected edge {i,j} live in thread
// g's REGISTERS for all steps: in_new = F(u_j - out_old), out_new =
// F(u_i - in_old); u_i is computed redundantly by all 16 threads of node i
// anyway. Removes the em gather (one of two serial MALL round-trips/step),
// the per-step em store, em ping-pong and zero-init. em materialized once at
// the last step for the epilogue. (b) Barrier 1 removed: rsj (neighbor row
// sum) recomputed locally from J (16 parallel L2 reads) instead of gathering
// fA[j] published by other blocks. 12 -> 11 grid barriers.
// Barrier: distributed flags (R10), agent-scope relaxed cache-bypass ld/st,
// no fences (vmcnt drain at s_barrier is the release point).

__device__ __forceinline__ float lse2(float a, float b) {
    return fmaxf(a, b) + __logf(1.0f + __expf(-fabsf(a - b)));
}

// agent-scope write-through / cache-bypass 8B accessors
__device__ __forceinline__ void stA(float2* p, float2 v) {
    union { float2 f; unsigned long long u; } x; x.f = v;
    __hip_atomic_store((unsigned long long*)p, x.u,
                       __ATOMIC_RELAXED, __HIP_MEMORY_SCOPE_AGENT);
}
__device__ __forceinline__ float2 ldA(const float2* p) {
    union { float2 f; unsigned long long u; } x;
    x.u = __hip_atomic_load((const unsigned long long*)p,
                            __ATOMIC_RELAXED, __HIP_MEMORY_SCOPE_AGENT);
    return x.f;
}

struct KParams {
    const float *J, *bias, *gat_W, *gat_a, *W1, *b1, *W2, *b2, *W3, *b3;
    const int *col, *rev, *ru, *cu, *u2e;
    int N, Eu;
    float2 *jsC, *uA, *uB, *em;
    int*    bar;                 // NB flags, 128B apart, pre-zeroed
    float  *ci_out, *dom_out, *ent;
    float2* ro_out;
    float4* rp_out;
    float*  cij_out;
};

// Distributed-flag grid barrier (no RMW, no fences). Monotone ordinals.
__device__ __forceinline__ void grid_bar(int* flags, int expect) {
    __syncthreads();                          // drains all waves' vmem stores
    if (threadIdx.x == 0)
        __hip_atomic_store(&flags[blockIdx.x * 32], expect,
                           __ATOMIC_RELAXED, __HIP_MEMORY_SCOPE_AGENT);
    if (threadIdx.x < NB) {
        while (__hip_atomic_load(&flags[threadIdx.x * 32], __ATOMIC_RELAXED,
                                 __HIP_MEMORY_SCOPE_AGENT) < expect) {}
    }
    __syncthreads();
}

__global__ __launch_bounds__(TB) void k_fused(KParams p) {
    __shared__ float sW2[64 * 64];
    __shared__ float sh1[TB / 16][65];
    __shared__ float red[TB / 64];

    const int tidb = threadIdx.x;
    const int g = blockIdx.x * TB + tidb;
    const int i = g >> 4, t = g & 15;
    const int lane = tidb & 63;

    // ---------------- setup: per-node + per-edge params (no cross-block) ----
    for (int k = tidb; k < 64 * 64; k += TB) sW2[k] = p.W2[k];
    if (g < 3) {  // agent-scope store: must reach MALL before later atomicAdds
        __hip_atomic_store((int*)&p.ent[g], 0,
                           __ATOMIC_RELAXED, __HIP_MEMORY_SCOPE_AGENT);
    }

    const int j  = p.col[g];
    const float Jv = p.J[(size_t)i * (size_t)p.N + (size_t)j];

    float rs = Jv;                            // row-sum of node i (16 nnz)
    rs += __shfl_xor(rs, 1); rs += __shfl_xor(rs, 2);
    rs += __shfl_xor(rs, 4); rs += __shfl_xor(rs, 8);

    float rsj = 0.0f;                         // row-sum of neighbor j (local)
    {
        const int* colj = p.col + 16 * j;
        const float* Jrow = p.J + (size_t)j * (size_t)p.N;
        #pragma unroll 4
        for (int tt = 0; tt < 16; ++tt) rsj += Jrow[colj[tt]];
    }

    const float bi = p.bias[i], bj = p.bias[j];

    float s8 = 0.0f;                          // gat_W^T @ gat_a halves
    if (lane < 8) {
        int k = lane & 3;
        const float* a = p.gat_a + ((lane < 4) ? 0 : 64);
        for (int h = 0; h < 64; ++h) s8 += p.gat_W[k * 64 + h] * a[h];
    }
    const float w10 = __shfl(s8, 0), w11 = __shfl(s8, 1), w12 = __shfl(s8, 2), w13 = __shfl(s8, 3);
    const float w20 = __shfl(s8, 4), w21 = __shfl(s8, 5), w22 = __shfl(s8, 6), w23 = __shfl(s8, 7);
    const float fd = 16.0f;
    const float f1i = -bi * w10 + bi * w11 + fd * w12 + rs  * w13;
    const float f2i = -bi * w20 + bi * w21 + fd * w22 + rs  * w23;
    const float f1j = -bj * w10 + bj * w11 + fd * w12 + rsj * w13;
    const float f2j = -bj * w20 + bj * w21 + fd * w22 + rsj * w23;

    float x1 = f1i + f2j; x1 = (x1 > 0.0f) ? x1 : 0.2f * x1;
    float x2 = f1j + f2i; x2 = (x2 > 0.0f) ? x2 : 0.2f * x2;
    const float C  = 0.5f * (__expf(x1) + __expf(x2));   // symmetric g <-> rev[g]
    const float js = Jv / C;
    stA(&p.jsC[g], make_float2(js, C));       // for epilogue (foreign reads)

    float sc = C;
    sc += __shfl_xor(sc, 1); sc += __shfl_xor(sc, 2);
    sc += __shfl_xor(sc, 4); sc += __shfl_xor(sc, 8);

    // Ci readout MLP (per node, 16 threads per node)
    const int nib = tidb >> 4;
    __syncthreads();                          // sW2 staged
    #pragma unroll
    for (int m = 0; m < 4; ++m) {
        int h = t + 16 * m;
        float a = -bi * p.W1[h] + bi * p.W1[64 + h] + fd * p.W1[128 + h]
                + rs * p.W1[192 + h] + p.b1[h];
        sh1[nib][h] = fmaxf(a, 0.0f);
    }
    __syncthreads();
    float civ = 0.0f;
    #pragma unroll
    for (int m = 0; m < 4; ++m) {
        int o = t + 16 * m;
        float acc = p.b2[o];
        for (int h = 0; h < 64; ++h) acc += sh1[nib][h] * sW2[h * 64 + o];
        civ += fmaxf(acc, 0.0f) * p.W3[o];
    }
    civ += __shfl_xor(civ, 1); civ += __shfl_xor(civ, 2);
    civ += __shfl_xor(civ, 4); civ += __shfl_xor(civ, 8);
    const float ci = civ + p.b3[0];

    const float s  = ci + sc;
    const float cl = fmaxf(fabsf(s), 0.1f);
    const float d  = (s > 0.0f) ? cl : ((s < 0.0f) ? -cl : 0.0f);
    const float rd = 1.0f / d;
    const float bs = bi * rd;
    if (t == 0) {
        p.ci_out[i] = ci;                     // outputs (plain stores)
        p.dom_out[i] = d;
        stA(&p.uA[i], make_float2(-bs, bs));  // u0 = bx_scale (em0 = 0)
    }
    grid_bar(p.bar, 1);                       // u0, jsC visible grid-wide

    // prefetch epilogue operands (independent of BP steps)
    int eE = 0, eR = 0, eC = 0, eEr = 0;
    float jse = 0.0f, Ce = 0.0f;
    if (g < p.Eu) {
        eE = p.u2e[g]; eR = p.ru[g]; eC = p.cu[g];
        eEr = p.rev[eE];                      // read-only input array
        const float2 jc = ldA(&p.jsC[eE]);
        jse = jc.x; Ce = jc.y;
    }

    // ---------------- BP steps: both edge messages in registers -------------
    float in0 = 0.0f, in1 = 0.0f;             // msg j->i (slot g)
    float out0 = 0.0f, out1 = 0.0f;           // msg i->j (slot rev[g])
    float ui0 = -bs, ui1 = bs;                // u[i], tracked by every thread
    float2 *uP = p.uA, *uQ = p.uB;
    for (int st = 0; st < NSTEP; ++st) {
        const float2 uj = ldA(&uP[j]);        // the ONLY gather per step
        // in_new = F(u_j - out_old)
        const float a0 = uj.x - out0, a1 = uj.y - out1;
        const float t0 = fmaxf( js + a0, -js + a1);
        const float t1 = fmaxf(-js + a0,  js + a1);
        const float ls = lse2(t0, t1);
        const float ni0 = C * (t0 - ls), ni1 = C * (t1 - ls);
        // out_new = F(u_i - in_old)   (u_i, in_old both in registers)
        const float b0 = ui0 - in0, b1 = ui1 - in1;
        const float q0 = fmaxf( js + b0, -js + b1);
        const float q1 = fmaxf(-js + b0,  js + b1);
        const float qs = lse2(q0, q1);
        out0 = C * (q0 - qs); out1 = C * (q1 - qs);
        in0 = ni0; in1 = ni1;

        float nm0 = in0, nm1 = in1;           // node's 16 incoming messages
        nm0 += __shfl_xor(nm0, 1); nm1 += __shfl_xor(nm1, 1);
        nm0 += __shfl_xor(nm0, 2); nm1 += __shfl_xor(nm1, 2);
        nm0 += __shfl_xor(nm0, 4); nm1 += __shfl_xor(nm1, 4);
        nm0 += __shfl_xor(nm0, 8); nm1 += __shfl_xor(nm1, 8);
        ui0 = -bs + nm0 * rd; ui1 = bs + nm1 * rd;
        if (t == 0) stA(&uQ[i], make_float2(ui0, ui1));

        if (st == NSTEP - 1) {
            stA(&p.em[g], make_float2(in0, in1));  // materialize for epilogue
            float nodeC = 0.0f;
            if (t == 0) {                     // node readout + node entropy
                const float lz = lse2(ui0, ui1);
                const float r0 = __expf(ui0 - lz), r1 = __expf(ui1 - lz);
                p.ro_out[i] = make_float2(r0, r1);
                const float H = -(r0 * __logf(r0 + 1e-16f) + r1 * __logf(r1 + 1e-16f));
                nodeC = ci * H;
            }
            for (int off = 32; off > 0; off >>= 1) nodeC += __shfl_down(nodeC, off);
            const int wv = tidb >> 6;
            if (lane == 0) red[wv] = nodeC;
            __syncthreads();
            if (tidb == 0) {
                float sn = 0.0f;
                #pragma unroll
                for (int w = 0; w < TB / 64; ++w) sn += red[w];
                atomicAdd(&p.ent[0], sn);
                atomicAdd(&p.ent[1], sn);
            }
        }
        grid_bar(p.bar, 2 + st);              // step st results visible
        float2* tp = uP; uP = uQ; uQ = tp;
    }
    // uP holds final u; p.em holds final messages

    // ---------------- epilogue: pairwise readout + edge entropy -------------
    float edgeC = 0.0f;
    if (g < p.Eu) {
        const float2 uc = ldA(&uP[eC]), ur = ldA(&uP[eR]);
        const float lc = lse2(uc.x, uc.y);
        const float lr = lse2(ur.x, ur.y);
        const float2 eme = ldA(&p.em[eEr]);   // message on edge e at slot rev[e]
        const float2 emr = ldA(&p.em[eE]);    // message on rev[e] at slot e
        const float ti0 = (uc.x - lc) - eme.x, ti1 = (uc.y - lc) - eme.y;
        const float tj0 = (ur.x - lr) - emr.x, tj1 = (ur.y - lr) - emr.y;
        const float L00 =  jse + ti0 + tj0;
        const float L01 = -jse + ti1 + tj0;
        const float L10 = -jse + ti0 + tj1;
        const float L11 =  jse + ti1 + tj1;
        const float mL = fmaxf(fmaxf(L00, L01), fmaxf(L10, L11));
        float p00 = __expf(L00 - mL), p01 = __expf(L01 - mL);
        float p10 = __expf(L10 - mL), p11 = __expf(L11 - mL);
        const float inv = 1.0f / (p00 + p01 + p10 + p11);
        p00 *= inv; p01 *= inv; p10 *= inv; p11 *= inv;
        p.rp_out[g] = make_float4(p00, p01, p10, p11);
        p.cij_out[g] = Ce;
        const float H = -(p00 * __logf(p00 + 1e-16f) + p01 * __logf(p01 + 1e-16f)
                        + p10 * __logf(p10 + 1e-16f) + p11 * __logf(p11 + 1e-16f));
        edgeC = Ce * H;
    }
    for (int off = 32; off > 0; off >>= 1) edgeC += __shfl_down(edgeC, off);
    const int wv = tidb >> 6;
    if (lane == 0) red[wv] = edgeC;
    __syncthreads();
    if (tidb == 0) {
        float se = 0.0f;
        #pragma unroll
        for (int w = 0; w < TB / 64; ++w) se += red[w];
        atomicAdd(&p.ent[0], se);
        atomicAdd(&p.ent[2], se);
    }
}

extern "C" void kernel_launch(void* const* d_in, const int* in_sizes, int n_in,
                              void* d_out, int out_size, void* d_ws, size_t ws_size,
                              hipStream_t stream) {
    const int N  = in_sizes[1];
    const int E  = in_sizes[10];
    const int Eu = in_sizes[13];

    float* out = (float*)d_out;
    size_t OFF_RP  = 2 * (size_t)N;
    size_t OFF_ENT = OFF_RP + 4 * (size_t)Eu;

    char* w = (char*)d_ws;
    auto carve = [&](size_t bytes) {
        void* q = (void*)w;
        w += (bytes + 255) & ~(size_t)255;
        return q;
    };

    KParams p;
    p.J     = (const float*)d_in[0];
    p.bias  = (const float*)d_in[1];
    p.gat_W = (const float*)d_in[2];
    p.gat_a = (const float*)d_in[3];
    p.W1    = (const float*)d_in[4];
    p.b1    = (const float*)d_in[5];
    p.W2    = (const float*)d_in[6];
    p.b2    = (const float*)d_in[7];
    p.W3    = (const float*)d_in[8];
    p.b3    = (const float*)d_in[9];
    p.col   = (const int*)d_in[11];
    p.rev   = (const int*)d_in[12];
    p.ru    = (const int*)d_in[13];
    p.cu    = (const int*)d_in[14];
    p.u2e   = (const int*)d_in[15];
    p.N = N; p.Eu = Eu;

    p.jsC   = (float2*)carve((size_t)E * 8);
    p.uA    = (float2*)carve((size_t)N * 8);
    p.uB    = (float2*)carve((size_t)N * 8);
    p.em    = (float2*)carve((size_t)E * 8);
    p.bar   = (int*)carve((size_t)NB * 128);  // NB flags, 128B apart

    p.ro_out  = (float2*)out;
    p.rp_out  = (float4*)(out + OFF_RP);
    p.ent     = out + OFF_ENT;
    p.ci_out  = p.ent + 3;
    p.cij_out = p.ci_out + N;
    p.dom_out = p.cij_out + Eu;

    hipMemsetAsync(p.bar, 0, (size_t)NB * 128, stream);
    k_fused<<<dim3(NB), dim3(TB), 0, stream>>>(p);
}

// Round 7
// 157.233 us; speedup vs baseline: 2.1987x; 1.0202x over previous
//
#include <hip/hip_runtime.h>
#include <cstddef>

#define TB    512
#define NB    128
#define NSTEP 10
#define SENTV 0xFFFFFFFFFFFFFFFFULL
// Problem constants: N=4096, E=65536 (=N*16, uniform degree 16, row-major
// sorted so out-edges of node i are slots [16i,16i+16)), Eu=32768.
// Slot scheme: em slot g (g=16i+t) holds the message on edge rev[g]=(j->i).
// We propagate u = hidden + lnZ; hidden recovered as u - lse(u) at readout.
// R13: SELF-ANNOUNCING DATA. No barriers, no flags, no fences. Every
// cross-block datum (fA, jsC, u per step, em) is write-once into a
// sentinel-initialized slot (one memset 0xFF over the whole region);
// consumers poll the datum's own bits != sentinel. The successful poll IS
// the data load -> zero ordering requirements beyond 8B store atomicity.
// u gets NSTEP+1 distinct buffers (write-once) -> no WAR, nodes free-run,
// steps pipeline through the graph. rsj gather replaced by polling fA[j]
// (published pre-MLP, polled post-MLP -> latency hidden). Poll backoff:
// tight first check, then s_sleep(1) between retries.
// Both directed edge messages stay in registers (R11 recurrence).

__device__ __forceinline__ float lse2(float a, float b) {
    return fmaxf(a, b) + __logf(1.0f + __expf(-fabsf(a - b)));
}

// agent-scope write-through / cache-bypass 8B store
__device__ __forceinline__ void stA(float2* p, float2 v) {
    union { float2 f; unsigned long long u; } x; x.f = v;
    __hip_atomic_store((unsigned long long*)p, x.u,
                       __ATOMIC_RELAXED, __HIP_MEMORY_SCOPE_AGENT);
}
// poll the datum itself until its bits != sentinel; returns the value
__device__ __forceinline__ float2 pollLd(const float2* p) {
    union { float2 f; unsigned long long u; } x;
    x.u = __hip_atomic_load((const unsigned long long*)p,
                            __ATOMIC_RELAXED, __HIP_MEMORY_SCOPE_AGENT);
    while (x.u == SENTV) {
        __builtin_amdgcn_s_sleep(1);
        x.u = __hip_atomic_load((const unsigned long long*)p,
                                __ATOMIC_RELAXED, __HIP_MEMORY_SCOPE_AGENT);
    }
    return x.f;
}

struct KParams {
    const float *J, *bias, *gat_W, *gat_a, *W1, *b1, *W2, *b2, *W3, *b3;
    const int *col, *rev, *ru, *cu, *u2e;
    int N, Eu;
    float2 *fA, *jsC, *em, *uS;   // uS: (NSTEP+1) x N, all sentinel-init
    float  *ci_out, *dom_out, *ent;
    float2* ro_out;
    float4* rp_out;
    float*  cij_out;
};

__global__ __launch_bounds__(TB) void k_fused(KParams p) {
    __shared__ float sW2[64 * 64];
    __shared__ float sh1[TB / 16][65];
    __shared__ float red[TB / 64];

    const int tidb = threadIdx.x;
    const int g = blockIdx.x * TB + tidb;
    const int i = g >> 4, t = g & 15;
    const int lane = tidb & 63;
    const int N = p.N;

    // ---------------- setup ------------------------------------------------
    for (int k = tidb; k < 64 * 64; k += TB) sW2[k] = p.W2[k];
    if (g < 3) {  // zero entropy accumulators early; adds happen >>later
        __hip_atomic_store((int*)&p.ent[g], 0,
                           __ATOMIC_RELAXED, __HIP_MEMORY_SCOPE_AGENT);
    }

    const int j  = p.col[g];
    const float Jv = p.J[(size_t)i * (size_t)N + (size_t)j];

    float rs = Jv;                            // row-sum of node i (16 nnz)
    rs += __shfl_xor(rs, 1); rs += __shfl_xor(rs, 2);
    rs += __shfl_xor(rs, 4); rs += __shfl_xor(rs, 8);

    const float bi = p.bias[i];

    float s8 = 0.0f;                          // gat_W^T @ gat_a halves
    if (lane < 8) {
        int k = lane & 3;
        const float* a = p.gat_a + ((lane < 4) ? 0 : 64);
        for (int h = 0; h < 64; ++h) s8 += p.gat_W[k * 64 + h] * a[h];
    }
    const float w10 = __shfl(s8, 0), w11 = __shfl(s8, 1), w12 = __shfl(s8, 2), w13 = __shfl(s8, 3);
    const float w20 = __shfl(s8, 4), w21 = __shfl(s8, 5), w22 = __shfl(s8, 6), w23 = __shfl(s8, 7);
    const float fd = 16.0f;
    const float f1i = -bi * w10 + bi * w11 + fd * w12 + rs * w13;
    const float f2i = -bi * w20 + bi * w21 + fd * w22 + rs * w23;
    if (t == 0) stA(&p.fA[i], make_float2(f1i, f2i));   // publish EARLY

    // Ci readout MLP (per node, 16 threads per node) — hides fA poll latency
    const int nib = tidb >> 4;
    __syncthreads();                          // sW2 staged
    #pragma unroll
    for (int m = 0; m < 4; ++m) {
        int h = t + 16 * m;
        float a = -bi * p.W1[h] + bi * p.W1[64 + h] + fd * p.W1[128 + h]
                + rs * p.W1[192 + h] + p.b1[h];
        sh1[nib][h] = fmaxf(a, 0.0f);
    }
    __syncthreads();
    float civ = 0.0f;
    #pragma unroll
    for (int m = 0; m < 4; ++m) {
        int o = t + 16 * m;
        float acc = p.b2[o];
        for (int h = 0; h < 64; ++h) acc += sh1[nib][h] * sW2[h * 64 + o];
        civ += fmaxf(acc, 0.0f) * p.W3[o];
    }
    civ += __shfl_xor(civ, 1); civ += __shfl_xor(civ, 2);
    civ += __shfl_xor(civ, 4); civ += __shfl_xor(civ, 8);
    const float ci = civ + p.b3[0];

    const float2 fj = pollLd(&p.fA[j]);       // neighbor features (poll)
    float x1 = f1i + fj.y; x1 = (x1 > 0.0f) ? x1 : 0.2f * x1;
    float x2 = fj.x + f2i; x2 = (x2 > 0.0f) ? x2 : 0.2f * x2;
    const float C  = 0.5f * (__expf(x1) + __expf(x2));   // symmetric g <-> rev[g]
    const float js = Jv / C;
    stA(&p.jsC[g], make_float2(js, C));       // for epilogue (foreign reads)

    float sc = C;
    sc += __shfl_xor(sc, 1); sc += __shfl_xor(sc, 2);
    sc += __shfl_xor(sc, 4); sc += __shfl_xor(sc, 8);
    const float s  = ci + sc;
    const float cl = fmaxf(fabsf(s), 0.1f);
    const float d  = (s > 0.0f) ? cl : ((s < 0.0f) ? -cl : 0.0f);
    const float rd = 1.0f / d;
    const float bs = bi * rd;
    if (t == 0) {
        p.ci_out[i] = ci;                     // outputs (plain stores)
        p.dom_out[i] = d;
        stA(&p.uS[i], make_float2(-bs, bs));  // u^0 = bx_scale (em0 = 0)
    }

    // prefetch epilogue indices (read-only inputs, independent)
    int eE = 0, eR = 0, eC = 0, eEr = 0;
    if (g < p.Eu) {
        eE = p.u2e[g]; eR = p.ru[g]; eC = p.cu[g];
        eEr = p.rev[eE];
    }

    // ---------------- BP steps: free-running, write-once u per step ---------
    float in0 = 0.0f, in1 = 0.0f;             // msg j->i (slot g)
    float out0 = 0.0f, out1 = 0.0f;           // msg i->j (slot rev[g])
    float ui0 = -bs, ui1 = bs;                // u[i], tracked by every thread
    for (int st = 0; st < NSTEP; ++st) {
        const float2 uj = pollLd(&p.uS[(size_t)st * N + j]);  // self-announcing
        // in_new = F(u_j - out_old)
        const float a0 = uj.x - out0, a1 = uj.y - out1;
        const float t0 = fmaxf( js + a0, -js + a1);
        const float t1 = fmaxf(-js + a0,  js + a1);
        const float ls = lse2(t0, t1);
        const float ni0 = C * (t0 - ls), ni1 = C * (t1 - ls);
        // out_new = F(u_i - in_old)   (u_i, in_old both in registers)
        const float b0 = ui0 - in0, b1 = ui1 - in1;
        const float q0 = fmaxf( js + b0, -js + b1);
        const float q1 = fmaxf(-js + b0,  js + b1);
        const float qs = lse2(q0, q1);
        out0 = C * (q0 - qs); out1 = C * (q1 - qs);
        in0 = ni0; in1 = ni1;

        float nm0 = in0, nm1 = in1;           // node's 16 incoming messages
        nm0 += __shfl_xor(nm0, 1); nm1 += __shfl_xor(nm1, 1);
        nm0 += __shfl_xor(nm0, 2); nm1 += __shfl_xor(nm1, 2);
        nm0 += __shfl_xor(nm0, 4); nm1 += __shfl_xor(nm1, 4);
        nm0 += __shfl_xor(nm0, 8); nm1 += __shfl_xor(nm1, 8);
        ui0 = -bs + nm0 * rd; ui1 = bs + nm1 * rd;
        if (t == 0) stA(&p.uS[(size_t)(st + 1) * N + i], make_float2(ui0, ui1));
        if (st == NSTEP - 1) stA(&p.em[g], make_float2(in0, in1));
    }

    // ---------------- node readout + node entropy ---------------------------
    float nodeC = 0.0f;
    if (t == 0) {
        const float lz = lse2(ui0, ui1);
        const float r0 = __expf(ui0 - lz), r1 = __expf(ui1 - lz);
        p.ro_out[i] = make_float2(r0, r1);
        const float H = -(r0 * __logf(r0 + 1e-16f) + r1 * __logf(r1 + 1e-16f));
        nodeC = ci * H;
    }
    for (int off = 32; off > 0; off >>= 1) nodeC += __shfl_down(nodeC, off);
    {
        const int wv = tidb >> 6;
        if (lane == 0) red[wv] = nodeC;
        __syncthreads();
        if (tidb == 0) {
            float sn = 0.0f;
            #pragma unroll
            for (int w = 0; w < TB / 64; ++w) sn += red[w];
            atomicAdd(&p.ent[0], sn);
            atomicAdd(&p.ent[1], sn);
        }
        __syncthreads();                      // protect red[] reuse below
    }

    // ---------------- epilogue: pairwise readout + edge entropy -------------
    const float2* uF = p.uS + (size_t)NSTEP * N;
    float edgeC = 0.0f;
    if (g < p.Eu) {
        const float2 jc = pollLd(&p.jsC[eE]);
        const float jse = jc.x, Ce = jc.y;
        const float2 uc = pollLd(&uF[eC]), ur = pollLd(&uF[eR]);
        const float2 eme = pollLd(&p.em[eEr]);  // msg on edge e at slot rev[e]
        const float2 emr = pollLd(&p.em[eE]);   // msg on rev[e] at slot e
        const float lc = lse2(uc.x, uc.y);
        const float lr = lse2(ur.x, ur.y);
        const float ti0 = (uc.x - lc) - eme.x, ti1 = (uc.y - lc) - eme.y;
        const float tj0 = (ur.x - lr) - emr.x, tj1 = (ur.y - lr) - emr.y;
        const float L00 =  jse + ti0 + tj0;
        const float L01 = -jse + ti1 + tj0;
        const float L10 = -jse + ti0 + tj1;
        const float L11 =  jse + ti1 + tj1;
        const float mL = fmaxf(fmaxf(L00, L01), fmaxf(L10, L11));
        float p00 = __expf(L00 - mL), p01 = __expf(L01 - mL);
        float p10 = __expf(L10 - mL), p11 = __expf(L11 - mL);
        const float inv = 1.0f / (p00 + p01 + p10 + p11);
        p00 *= inv; p01 *= inv; p10 *= inv; p11 *= inv;
        p.rp_out[g] = make_float4(p00, p01, p10, p11);
        p.cij_out[g] = Ce;
        const float H = -(p00 * __logf(p00 + 1e-16f) + p01 * __logf(p01 + 1e-16f)
                        + p10 * __logf(p10 + 1e-16f) + p11 * __logf(p11 + 1e-16f));
        edgeC = Ce * H;
    }
    for (int off = 32; off > 0; off >>= 1) edgeC += __shfl_down(edgeC, off);
    const int wv = tidb >> 6;
    if (lane == 0) red[wv] = edgeC;
    __syncthreads();
    if (tidb == 0) {
        float se = 0.0f;
        #pragma unroll
        for (int w = 0; w < TB / 64; ++w) se += red[w];
        atomicAdd(&p.ent[0], se);
        atomicAdd(&p.ent[2], se);
    }
}

extern "C" void kernel_launch(void* const* d_in, const int* in_sizes, int n_in,
                              void* d_out, int out_size, void* d_ws, size_t ws_size,
                              hipStream_t stream) {
    const int N  = in_sizes[1];
    const int E  = in_sizes[10];
    const int Eu = in_sizes[13];

    float* out = (float*)d_out;
    size_t OFF_RP  = 2 * (size_t)N;
    size_t OFF_ENT = OFF_RP + 4 * (size_t)Eu;

    char* w = (char*)d_ws;
    auto carve = [&](size_t bytes) {
        void* q = (void*)w;
        w += (bytes + 255) & ~(size_t)255;
        return q;
    };

    KParams p;
    p.J     = (const float*)d_in[0];
    p.bias  = (const float*)d_in[1];
    p.gat_W = (const float*)d_in[2];
    p.gat_a = (const float*)d_in[3];
    p.W1    = (const float*)d_in[4];
    p.b1    = (const float*)d_in[5];
    p.W2    = (const float*)d_in[6];
    p.b2    = (const float*)d_in[7];
    p.W3    = (const float*)d_in[8];
    p.b3    = (const float*)d_in[9];
    p.col   = (const int*)d_in[11];
    p.rev   = (const int*)d_in[12];
    p.ru    = (const int*)d_in[13];
    p.cu    = (const int*)d_in[14];
    p.u2e   = (const int*)d_in[15];
    p.N = N; p.Eu = Eu;

    // contiguous sentinel region: fA | jsC | em | uS  (all 256B-multiples)
    const size_t szFA = (size_t)N * 8;                 // 32 KB
    const size_t szJC = (size_t)E * 8;                 // 512 KB
    const size_t szEM = (size_t)E * 8;                 // 512 KB
    const size_t szUS = (size_t)(NSTEP + 1) * N * 8;   // 352 KB
    p.fA  = (float2*)carve(szFA);
    p.jsC = (float2*)carve(szJC);
    p.em  = (float2*)carve(szEM);
    p.uS  = (float2*)carve(szUS);

    p.ro_out  = (float2*)out;
    p.rp_out  = (float4*)(out + OFF_RP);
    p.ent     = out + OFF_ENT;
    p.ci_out  = p.ent + 3;
    p.cij_out = p.ci_out + N;
    p.dom_out = p.cij_out + Eu;

    // one memset: sentinel-fill every cross-block buffer (write-once slots)
    hipMemsetAsync(p.fA, 0xFF, szFA + szJC + szEM + szUS, stream);
    k_fused<<<dim3(NB), dim3(TB), 0, stream>>>(p);
}